// Round 1
// baseline (494.084 us; speedup 1.0000x reference)
//
#include <hip/hip_runtime.h>
#include <hip/hip_bf16.h>
#include <math.h>

#define N_NODES 50000
#define N_EDGES 1600000
#define IN_CH 128
#define OUT_SZ 64

// monotone f32 -> u32 mapping for atomicMax on floats
__device__ __forceinline__ unsigned fenc(float x) {
    unsigned u = __float_as_uint(x);
    return (u & 0x80000000u) ? ~u : (u | 0x80000000u);
}
__device__ __forceinline__ float fdec(unsigned u) {
    return __uint_as_float((u & 0x80000000u) ? (u & 0x7fffffffu) : ~u);
}

// ---------------- K0: init softmax scalars ----------------
__global__ void k_init(unsigned* pmax, float* psum) {
    *pmax = 0u;       // fenc(-inf) < fenc(any finite) ; 0 is below all encodings of reals
    *psum = 0.0f;
}

// ---------------- K1: per-node linears ----------------
// one wave handles 4 nodes; lane = output channel (0..63)
// W staged in LDS as [i][c ^ (i&31)], c in [0,128): c<64 -> W_seq, c>=64 -> W_res
__global__ __launch_bounds__(256) void k_node(
    const float* __restrict__ seq, const float* __restrict__ Wseq,
    const float* __restrict__ Wres, const float* __restrict__ wf1,
    const float* __restrict__ bf1, const float* __restrict__ wf2,
    const float* __restrict__ bf2, const float* __restrict__ bias,
    const float* __restrict__ bres,
    float* __restrict__ sfts, float* __restrict__ f1, float* __restrict__ f2,
    float* __restrict__ out)
{
    __shared__ float W[IN_CH * 128];
    const int t = threadIdx.x;
#pragma unroll
    for (int k = 0; k < 64; ++k) {
        int idx = t + k * 256;          // 16384 = 128 ch * 128 i
        int c = idx >> 7;               // output channel 0..127
        int i = idx & 127;              // input channel, consecutive across lanes -> coalesced
        float v = (c < 64) ? Wseq[c * IN_CH + i] : Wres[(c - 64) * IN_CH + i];
        W[i * 128 + (c ^ (i & 31))] = v;   // swizzle: conflict-free write & read
    }
    __syncthreads();

    const int lane = t & 63;
    const int wv = t >> 6;
    const int n0 = (blockIdx.x * 4 + wv) * 4;     // 3125 blocks * 16 nodes = 50000 exactly
    if (n0 >= N_NODES) return;
    const float* s0p = seq + (size_t)n0 * IN_CH;

    float a00 = 0.f, a01 = 0.f, a10 = 0.f, a11 = 0.f;
    float a20 = 0.f, a21 = 0.f, a30 = 0.f, a31 = 0.f;
#pragma unroll 4
    for (int i = 0; i < IN_CH; ++i) {
        int sw = i * 128 + (lane ^ (i & 31));
        float w1 = W[sw];
        float w2 = W[sw + 64];
        float s0 = s0p[i];
        float s1 = s0p[IN_CH + i];
        float s2 = s0p[2 * IN_CH + i];
        float s3 = s0p[3 * IN_CH + i];
        a00 = fmaf(s0, w1, a00); a01 = fmaf(s0, w2, a01);
        a10 = fmaf(s1, w1, a10); a11 = fmaf(s1, w2, a11);
        a20 = fmaf(s2, w1, a20); a21 = fmaf(s2, w2, a21);
        a30 = fmaf(s3, w1, a30); a31 = fmaf(s3, w2, a31);
    }

    // f1/f2 dot-products over the 64 channels (lanes)
    float wl1 = wf1[lane], wl2 = wf2[lane];
    float r10 = a00 * wl1, r20 = a00 * wl2;
    float r11 = a10 * wl1, r21 = a10 * wl2;
    float r12 = a20 * wl1, r22 = a20 * wl2;
    float r13 = a30 * wl1, r23 = a30 * wl2;
#pragma unroll
    for (int off = 32; off; off >>= 1) {
        r10 += __shfl_xor(r10, off); r20 += __shfl_xor(r20, off);
        r11 += __shfl_xor(r11, off); r21 += __shfl_xor(r21, off);
        r12 += __shfl_xor(r12, off); r22 += __shfl_xor(r22, off);
        r13 += __shfl_xor(r13, off); r23 += __shfl_xor(r23, off);
    }

    float bb = bias[lane] + bres[lane];
    size_t o = (size_t)n0 * 64 + lane;
    sfts[o]       = a00;  out[o]       = a01 + bb;
    sfts[o + 64]  = a10;  out[o + 64]  = a11 + bb;
    sfts[o + 128] = a20;  out[o + 128] = a21 + bb;
    sfts[o + 192] = a30;  out[o + 192] = a31 + bb;

    if (lane == 0) {
        float B1 = bf1[0], B2 = bf2[0];
        f1[n0]     = r10 + B1;  f2[n0]     = r20 + B2;
        f1[n0 + 1] = r11 + B1;  f2[n0 + 1] = r21 + B2;
        f1[n0 + 2] = r12 + B1;  f2[n0 + 2] = r22 + B2;
        f1[n0 + 3] = r13 + B1;  f2[n0 + 3] = r23 + B2;
    }
}

// ---------------- K2: global max of leaky_relu(f1[src]+f2[dst]) ----------------
__global__ __launch_bounds__(256) void k_max(
    const int* __restrict__ ei, const float* __restrict__ f1,
    const float* __restrict__ f2, unsigned* pmax)
{
    int tid = blockIdx.x * 256 + threadIdx.x;
    int stride = gridDim.x * 256;
    float lm = -3.0e38f;
    for (int e = tid; e < N_EDGES; e += stride) {
        float x = f1[ei[e]] + f2[ei[N_EDGES + e]];
        x = (x > 0.f) ? x : 0.01f * x;
        lm = fmaxf(lm, x);
    }
#pragma unroll
    for (int off = 32; off; off >>= 1) lm = fmaxf(lm, __shfl_xor(lm, off));
    __shared__ float red[4];
    if ((threadIdx.x & 63) == 0) red[threadIdx.x >> 6] = lm;
    __syncthreads();
    if (threadIdx.x == 0) {
        lm = fmaxf(fmaxf(red[0], red[1]), fmaxf(red[2], red[3]));
        atomicMax(pmax, fenc(lm));
    }
}

// ---------------- K3: sum of exp(e - m) ----------------
__global__ __launch_bounds__(256) void k_sum(
    const int* __restrict__ ei, const float* __restrict__ f1,
    const float* __restrict__ f2, const unsigned* __restrict__ pmax,
    float* psum)
{
    float m = fdec(*pmax);
    int tid = blockIdx.x * 256 + threadIdx.x;
    int stride = gridDim.x * 256;
    float ls = 0.f;
    for (int e = tid; e < N_EDGES; e += stride) {
        float x = f1[ei[e]] + f2[ei[N_EDGES + e]];
        x = (x > 0.f) ? x : 0.01f * x;
        ls += __expf(x - m);
    }
#pragma unroll
    for (int off = 32; off; off >>= 1) ls += __shfl_xor(ls, off);
    __shared__ float red[4];
    if ((threadIdx.x & 63) == 0) red[threadIdx.x >> 6] = ls;
    __syncthreads();
    if (threadIdx.x == 0) {
        ls = red[0] + red[1] + red[2] + red[3];
        unsafeAtomicAdd(psum, ls);
    }
}

// ---------------- K4: scatter coef * seq_fts[dst] into out[src] ----------------
// one wave per edge iteration, lane = channel
__global__ __launch_bounds__(256) void k_scat(
    const int* __restrict__ ei, const float* __restrict__ f1,
    const float* __restrict__ f2, const float* __restrict__ sfts,
    const unsigned* __restrict__ pmax, const float* __restrict__ psum,
    float* __restrict__ out)
{
    float m = fdec(*pmax);
    float inv = 1.0f / (*psum);
    int lane = threadIdx.x & 63;
    int wave = (blockIdx.x * 256 + threadIdx.x) >> 6;
    int nw = (gridDim.x * 256) >> 6;
    for (int e = wave; e < N_EDGES; e += nw) {
        int src = ei[e];
        int dst = ei[N_EDGES + e];
        float x = f1[src] + f2[dst];
        x = (x > 0.f) ? x : 0.01f * x;
        float coef = __expf(x - m) * inv;
        float v = sfts[(size_t)dst * 64 + lane];
        unsafeAtomicAdd(out + (size_t)src * 64 + lane, coef * v);
    }
}

// ---------------- K5: in-place ELU ----------------
__global__ __launch_bounds__(256) void k_elu(float* __restrict__ out) {
    int i = blockIdx.x * 256 + threadIdx.x;
    if (i < N_NODES * OUT_SZ) {
        float x = out[i];
        out[i] = (x > 0.f) ? x : expm1f(x);
    }
}

extern "C" void kernel_launch(void* const* d_in, const int* in_sizes, int n_in,
                              void* d_out, int out_size, void* d_ws, size_t ws_size,
                              hipStream_t stream) {
    const float* seq  = (const float*)d_in[0];
    const int*   ei   = (const int*)d_in[1];
    const float* Wseq = (const float*)d_in[2];
    const float* wf1  = (const float*)d_in[3];
    const float* bf1  = (const float*)d_in[4];
    const float* wf2  = (const float*)d_in[5];
    const float* bf2  = (const float*)d_in[6];
    const float* bias = (const float*)d_in[7];
    const float* Wres = (const float*)d_in[8];
    const float* bres = (const float*)d_in[9];
    float* out = (float*)d_out;

    // ws layout (floats): [0]=pmax(u32) [1]=psum [16..] sfts(N*64), f1(N), f2(N)
    unsigned* pmax = (unsigned*)d_ws;
    float* psum = (float*)d_ws + 1;
    float* sfts = (float*)d_ws + 16;
    float* f1   = sfts + (size_t)N_NODES * 64;
    float* f2   = f1 + N_NODES;

    k_init<<<1, 1, 0, stream>>>(pmax, psum);
    k_node<<<3125, 256, 0, stream>>>(seq, Wseq, Wres, wf1, bf1, wf2, bf2, bias,
                                     bres, sfts, f1, f2, out);
    k_max<<<2048, 256, 0, stream>>>(ei, f1, f2, pmax);
    k_sum<<<2048, 256, 0, stream>>>(ei, f1, f2, pmax, psum);
    k_scat<<<16384, 256, 0, stream>>>(ei, f1, f2, sfts, pmax, psum, out);
    k_elu<<<12500, 256, 0, stream>>>(out);
}

// Round 2
// 419.610 us; speedup vs baseline: 1.1775x; 1.1775x over previous
//
#include <hip/hip_runtime.h>
#include <hip/hip_bf16.h>
#include <math.h>

#define N_NODES 50000
#define N_EDGES 1600000
#define IN_CH 128
#define OUT_SZ 64

// monotone f32 -> u32 mapping for atomicMax on floats
__device__ __forceinline__ unsigned fenc(float x) {
    unsigned u = __float_as_uint(x);
    return (u & 0x80000000u) ? ~u : (u | 0x80000000u);
}
__device__ __forceinline__ float fdec(unsigned u) {
    return __uint_as_float((u & 0x80000000u) ? (u & 0x7fffffffu) : ~u);
}

// ---------------- K0: zero counters + softmax scalars ----------------
__global__ __launch_bounds__(256) void k_zero(unsigned* pmax, float* psum,
                                              unsigned* counts) {
    int i = blockIdx.x * 256 + threadIdx.x;
    if (i < N_NODES) counts[i] = 0u;
    if (i == 0) { *pmax = 0u; *psum = 0.0f; }
}

// ---------------- K1: per-node linears ----------------
// one wave handles 4 nodes; lane = output channel (0..63)
__global__ __launch_bounds__(256) void k_node(
    const float* __restrict__ seq, const float* __restrict__ Wseq,
    const float* __restrict__ Wres, const float* __restrict__ wf1,
    const float* __restrict__ bf1, const float* __restrict__ wf2,
    const float* __restrict__ bf2, const float* __restrict__ bias,
    const float* __restrict__ bres,
    float* __restrict__ sfts, float* __restrict__ f1, float* __restrict__ f2,
    float* __restrict__ out)
{
    __shared__ float W[IN_CH * 128];
    const int t = threadIdx.x;
#pragma unroll
    for (int k = 0; k < 64; ++k) {
        int idx = t + k * 256;          // 16384 = 128 ch * 128 i
        int c = idx >> 7;
        int i = idx & 127;
        float v = (c < 64) ? Wseq[c * IN_CH + i] : Wres[(c - 64) * IN_CH + i];
        W[i * 128 + (c ^ (i & 31))] = v;
    }
    __syncthreads();

    const int lane = t & 63;
    const int wv = t >> 6;
    const int n0 = (blockIdx.x * 4 + wv) * 4;
    if (n0 >= N_NODES) return;
    const float* s0p = seq + (size_t)n0 * IN_CH;

    float a00 = 0.f, a01 = 0.f, a10 = 0.f, a11 = 0.f;
    float a20 = 0.f, a21 = 0.f, a30 = 0.f, a31 = 0.f;
#pragma unroll 4
    for (int i = 0; i < IN_CH; ++i) {
        int sw = i * 128 + (lane ^ (i & 31));
        float w1 = W[sw];
        float w2 = W[sw + 64];
        float s0 = s0p[i];
        float s1 = s0p[IN_CH + i];
        float s2 = s0p[2 * IN_CH + i];
        float s3 = s0p[3 * IN_CH + i];
        a00 = fmaf(s0, w1, a00); a01 = fmaf(s0, w2, a01);
        a10 = fmaf(s1, w1, a10); a11 = fmaf(s1, w2, a11);
        a20 = fmaf(s2, w1, a20); a21 = fmaf(s2, w2, a21);
        a30 = fmaf(s3, w1, a30); a31 = fmaf(s3, w2, a31);
    }

    float wl1 = wf1[lane], wl2 = wf2[lane];
    float r10 = a00 * wl1, r20 = a00 * wl2;
    float r11 = a10 * wl1, r21 = a10 * wl2;
    float r12 = a20 * wl1, r22 = a20 * wl2;
    float r13 = a30 * wl1, r23 = a30 * wl2;
#pragma unroll
    for (int off = 32; off; off >>= 1) {
        r10 += __shfl_xor(r10, off); r20 += __shfl_xor(r20, off);
        r11 += __shfl_xor(r11, off); r21 += __shfl_xor(r21, off);
        r12 += __shfl_xor(r12, off); r22 += __shfl_xor(r22, off);
        r13 += __shfl_xor(r13, off); r23 += __shfl_xor(r23, off);
    }

    float bb = bias[lane] + bres[lane];
    size_t o = (size_t)n0 * 64 + lane;
    sfts[o]       = a00;  out[o]       = a01 + bb;
    sfts[o + 64]  = a10;  out[o + 64]  = a11 + bb;
    sfts[o + 128] = a20;  out[o + 128] = a21 + bb;
    sfts[o + 192] = a30;  out[o + 192] = a31 + bb;

    if (lane == 0) {
        float B1 = bf1[0], B2 = bf2[0];
        f1[n0]     = r10 + B1;  f2[n0]     = r20 + B2;
        f1[n0 + 1] = r11 + B1;  f2[n0 + 1] = r21 + B2;
        f1[n0 + 2] = r12 + B1;  f2[n0 + 2] = r22 + B2;
        f1[n0 + 3] = r13 + B1;  f2[n0 + 3] = r23 + B2;
    }
}

// ---------------- K2: histogram src + global max (one edge pass) ----------------
__global__ __launch_bounds__(256) void k_histmax(
    const int* __restrict__ ei, const float* __restrict__ f1,
    const float* __restrict__ f2, unsigned* __restrict__ counts,
    unsigned* pmax)
{
    int tid = blockIdx.x * 256 + threadIdx.x;
    int stride = gridDim.x * 256;
    float lm = -3.0e38f;
    for (int e = tid; e < N_EDGES; e += stride) {
        int src = ei[e];
        int dst = ei[N_EDGES + e];
        float x = f1[src] + f2[dst];
        x = (x > 0.f) ? x : 0.01f * x;
        lm = fmaxf(lm, x);
        atomicAdd(&counts[src], 1u);
    }
#pragma unroll
    for (int off = 32; off; off >>= 1) lm = fmaxf(lm, __shfl_xor(lm, off));
    __shared__ float red[4];
    if ((threadIdx.x & 63) == 0) red[threadIdx.x >> 6] = lm;
    __syncthreads();
    if (threadIdx.x == 0) {
        lm = fmaxf(fmaxf(red[0], red[1]), fmaxf(red[2], red[3]));
        atomicMax(pmax, fenc(lm));
    }
}

// ---------------- K3: single-block scan (counts -> offs, cursor) ----------------
#define SCAN_T 1024
#define SCAN_PER 49   // 1024*49 = 50176 >= 50000
__global__ __launch_bounds__(SCAN_T) void k_scan(
    const unsigned* __restrict__ counts, unsigned* __restrict__ offs,
    unsigned* __restrict__ cursor)
{
    __shared__ unsigned bs[SCAN_T];
    const int t = threadIdx.x;
    unsigned loc[SCAN_PER];
    unsigned s = 0;
    const int base = t * SCAN_PER;
#pragma unroll
    for (int k = 0; k < SCAN_PER; ++k) {
        int i = base + k;
        unsigned c = (i < N_NODES) ? counts[i] : 0u;
        loc[k] = s;        // exclusive within thread
        s += c;
    }
    bs[t] = s;
    __syncthreads();
    for (int off = 1; off < SCAN_T; off <<= 1) {
        unsigned v = (t >= off) ? bs[t - off] : 0u;
        __syncthreads();
        bs[t] += v;
        __syncthreads();
    }
    unsigned prev = t ? bs[t - 1] : 0u;
#pragma unroll
    for (int k = 0; k < SCAN_PER; ++k) {
        int i = base + k;
        if (i < N_NODES) {
            unsigned o = prev + loc[k];
            offs[i] = o;
            cursor[i] = o;
        }
    }
    if (t == SCAN_T - 1) offs[N_NODES] = bs[SCAN_T - 1];
}

// ---------------- K4: place dst into src-sorted order + sum exp ----------------
__global__ __launch_bounds__(256) void k_placesum(
    const int* __restrict__ ei, const float* __restrict__ f1,
    const float* __restrict__ f2, const unsigned* __restrict__ pmax,
    unsigned* __restrict__ cursor, unsigned short* __restrict__ sDst,
    float* psum)
{
    float m = fdec(*pmax);
    int tid = blockIdx.x * 256 + threadIdx.x;
    int stride = gridDim.x * 256;
    float ls = 0.f;
    for (int e = tid; e < N_EDGES; e += stride) {
        int src = ei[e];
        int dst = ei[N_EDGES + e];
        float x = f1[src] + f2[dst];
        x = (x > 0.f) ? x : 0.01f * x;
        ls += __expf(x - m);
        unsigned pos = atomicAdd(&cursor[src], 1u);
        sDst[pos] = (unsigned short)dst;
    }
#pragma unroll
    for (int off = 32; off; off >>= 1) ls += __shfl_xor(ls, off);
    __shared__ float red[4];
    if ((threadIdx.x & 63) == 0) red[threadIdx.x >> 6] = ls;
    __syncthreads();
    if (threadIdx.x == 0) {
        ls = red[0] + red[1] + red[2] + red[3];
        unsafeAtomicAdd(psum, ls);
    }
}

// ---------------- K5: per-node accumulate + ELU (no atomics) ----------------
// one wave per node; lane = channel
__global__ __launch_bounds__(256) void k_acc(
    const unsigned* __restrict__ offs, const unsigned short* __restrict__ sDst,
    const float* __restrict__ f1, const float* __restrict__ f2,
    const float* __restrict__ sfts, const unsigned* __restrict__ pmax,
    const float* __restrict__ psum, float* __restrict__ out)
{
    const int lane = threadIdx.x & 63;
    const int n = (blockIdx.x * 256 + threadIdx.x) >> 6;
    if (n >= N_NODES) return;
    const float m = fdec(*pmax);
    const float inv = 1.0f / (*psum);
    const unsigned b = offs[n];
    const unsigned e = offs[n + 1];
    const float f1n = f1[n];

    float acc = 0.f;
    for (unsigned e0 = b; e0 < e; e0 += 64) {
        const int cnt = (int)min(64u, e - e0);
        int dst = 0;
        float coef = 0.f;
        if (lane < cnt) {
            dst = (int)sDst[e0 + lane];
            float x = f1n + f2[dst];
            x = (x > 0.f) ? x : 0.01f * x;
            coef = __expf(x - m) * inv;
        }
        for (int j = 0; j < cnt; ++j) {
            int d = __shfl(dst, j);
            float c = __shfl(coef, j);
            acc = fmaf(c, sfts[(size_t)d * 64 + lane], acc);
        }
    }
    const size_t idx = (size_t)n * 64 + lane;
    float x = out[idx] + acc;
    out[idx] = (x > 0.f) ? x : expm1f(x);
}

extern "C" void kernel_launch(void* const* d_in, const int* in_sizes, int n_in,
                              void* d_out, int out_size, void* d_ws, size_t ws_size,
                              hipStream_t stream) {
    const float* seq  = (const float*)d_in[0];
    const int*   ei   = (const int*)d_in[1];
    const float* Wseq = (const float*)d_in[2];
    const float* wf1  = (const float*)d_in[3];
    const float* bf1  = (const float*)d_in[4];
    const float* wf2  = (const float*)d_in[5];
    const float* bf2  = (const float*)d_in[6];
    const float* bias = (const float*)d_in[7];
    const float* Wres = (const float*)d_in[8];
    const float* bres = (const float*)d_in[9];
    float* out = (float*)d_out;

    // ws layout
    unsigned* pmax        = (unsigned*)d_ws;
    float*    psum        = (float*)d_ws + 1;
    unsigned* counts      = (unsigned*)d_ws + 16;
    unsigned* offs        = counts + N_NODES;          // N_NODES+1
    unsigned* cursor      = offs + N_NODES + 1;
    unsigned short* sDst  = (unsigned short*)(cursor + N_NODES);  // N_EDGES u16
    float*    sfts        = (float*)(sDst + N_EDGES);
    float*    f1          = sfts + (size_t)N_NODES * 64;
    float*    f2          = f1 + N_NODES;
    // total ~17 MB

    k_zero<<<196, 256, 0, stream>>>(pmax, psum, counts);
    k_node<<<3125, 256, 0, stream>>>(seq, Wseq, Wres, wf1, bf1, wf2, bf2, bias,
                                     bres, sfts, f1, f2, out);
    k_histmax<<<2048, 256, 0, stream>>>(ei, f1, f2, counts, pmax);
    k_scan<<<1, SCAN_T, 0, stream>>>(counts, offs, cursor);
    k_placesum<<<2048, 256, 0, stream>>>(ei, f1, f2, pmax, cursor, sDst, psum);
    k_acc<<<12500, 256, 0, stream>>>(offs, sDst, f1, f2, sfts, pmax, psum, out);
}